// Round 1
// baseline (261.759 us; speedup 1.0000x reference)
//
#include <hip/hip_runtime.h>
#include <hip/hip_bf16.h>
#include <hip/hip_fp16.h>

typedef _Float16 f16;
typedef _Float16 f16x4 __attribute__((ext_vector_type(4)));
typedef _Float16 f16x8 __attribute__((ext_vector_type(8)));
typedef float f32x4 __attribute__((ext_vector_type(4)));

#define MFMA16(a, b, c) __builtin_amdgcn_mfma_f32_16x16x32_f16(a, b, c, 0, 0, 0)

// ---------------- prep: f32 -> f16 convert ----------------
__global__ void k_convert_x(const float* __restrict__ in, f16* __restrict__ out, int n4) {
    int i = blockIdx.x * blockDim.x + threadIdx.x;
    if (i >= n4) return;
    float4 v = ((const float4*)in)[i];
    f16x4 o = {(f16)v.x, (f16)v.y, (f16)v.z, (f16)v.w};
    ((f16x4*)out)[i] = o;
}

// ---------------- prep: transpose f32[K][N] -> f16[N][K] ----------------
__global__ __launch_bounds__(256) void k_transpose(const float* __restrict__ in,
                                                   f16* __restrict__ out, int K, int N) {
    __shared__ f16 tile[64][72];
    int n0 = blockIdx.x * 64, k0 = blockIdx.y * 64;
    int t = threadIdx.x;
    int r = t >> 2, cb = (t & 3) * 16;
    const float* src = in + (size_t)(k0 + r) * N + n0 + cb;
#pragma unroll
    for (int j = 0; j < 4; ++j) {
        float4 v = ((const float4*)src)[j];
        tile[r][cb + 4 * j + 0] = (f16)v.x;
        tile[r][cb + 4 * j + 1] = (f16)v.y;
        tile[r][cb + 4 * j + 2] = (f16)v.z;
        tile[r][cb + 4 * j + 3] = (f16)v.w;
    }
    __syncthreads();
    int nl = t >> 2, kb = (t & 3) * 16;
    f16* dst = out + (size_t)(n0 + nl) * K + k0 + kb;
#pragma unroll
    for (int j = 0; j < 2; ++j) {
        f16x8 o;
#pragma unroll
        for (int e = 0; e < 8; ++e) o[e] = tile[kb + 8 * j + e][nl];
        *(f16x8*)(dst + 8 * j) = o;
    }
}

// ---------------- shared GEMM core: C(128x128) += A[M][768] * Bt[N][768]^T ----------------
__device__ __forceinline__ void gemm_core(const f16* __restrict__ A, const f16* __restrict__ Bt,
                                          int m0, int n0, int t, int lane, int wr, int wc,
                                          f16* As, f16* Bs, f32x4 acc[4][4]) {
    for (int kt = 0; kt < 24; ++kt) {
#pragma unroll
        for (int i = 0; i < 2; ++i) {
            int c = t + i * 256;
            int row = c >> 2, cb = (c & 3) * 8;
            f16x8 va = *(const f16x8*)(A + (size_t)(m0 + row) * 768 + kt * 32 + cb);
            f16x8 vb = *(const f16x8*)(Bt + (size_t)(n0 + row) * 768 + kt * 32 + cb);
            *(f16x8*)(As + row * 40 + cb) = va;
            *(f16x8*)(Bs + row * 40 + cb) = vb;
        }
        __syncthreads();
        f16x8 a[4], b[4];
#pragma unroll
        for (int i = 0; i < 4; ++i)
            a[i] = *(const f16x8*)(As + (wr * 64 + i * 16 + (lane & 15)) * 40 + (lane >> 4) * 8);
#pragma unroll
        for (int j = 0; j < 4; ++j)
            b[j] = *(const f16x8*)(Bs + (wc * 64 + j * 16 + (lane & 15)) * 40 + (lane >> 4) * 8);
#pragma unroll
        for (int i = 0; i < 4; ++i)
#pragma unroll
            for (int j = 0; j < 4; ++j) acc[i][j] = MFMA16(a[i], b[j], acc[i][j]);
        __syncthreads();
    }
}

// ---------------- QKV GEMM: xh[4096][768] x wqkv_t[2304][768]^T + bias -> Qh,Kh,Vt ----------------
__global__ __launch_bounds__(256) void k_qkv_gemm(const f16* __restrict__ A, const f16* __restrict__ Bt,
                                                  const float* __restrict__ bias,
                                                  f16* __restrict__ Qh, f16* __restrict__ Kh,
                                                  f16* __restrict__ Vt) {
    __shared__ f16 As[128 * 40];
    __shared__ f16 Bs[128 * 40];
    int m0 = blockIdx.x * 128, n0 = blockIdx.y * 128;
    int t = threadIdx.x, lane = t & 63, w = t >> 6;
    int wr = w >> 1, wc = w & 1;
    f32x4 zero = {0.f, 0.f, 0.f, 0.f};
    f32x4 acc[4][4];
#pragma unroll
    for (int i = 0; i < 4; ++i)
#pragma unroll
        for (int j = 0; j < 4; ++j) acc[i][j] = zero;

    gemm_core(A, Bt, m0, n0, t, lane, wr, wc, As, Bs, acc);

#pragma unroll
    for (int j = 0; j < 4; ++j) {
        int n = n0 + wc * 64 + j * 16 + (lane & 15);
        int which = n / 768;
        int rem = n - which * 768;
        int h = rem >> 6, d = rem & 63;
        float bv = bias[n];
#pragma unroll
        for (int i = 0; i < 4; ++i) {
            int m = m0 + wr * 64 + i * 16 + ((lane >> 4) << 2);
            int bb = m >> 11, tt = m & 2047;
            int bh = bb * 12 + h;
            if (which == 2) {
                f16x4 pk;
#pragma unroll
                for (int r = 0; r < 4; ++r) pk[r] = (f16)(acc[i][j][r] + bv);
                *(f16x4*)(Vt + ((size_t)bh * 64 + d) * 2048 + tt) = pk;
            } else if (which == 0) {
#pragma unroll
                for (int r = 0; r < 4; ++r)
                    Qh[((size_t)bh * 2048 + tt + r) * 64 + d] = (f16)((acc[i][j][r] + bv) * 0.125f);
            } else {
#pragma unroll
                for (int r = 0; r < 4; ++r)
                    Kh[((size_t)bh * 2048 + tt + r) * 64 + d] = (f16)(acc[i][j][r] + bv);
            }
        }
    }
}

// ---------------- O GEMM: valh[4096][768] x wo_t[768][768]^T + bias -> out fp32 ----------------
__global__ __launch_bounds__(256) void k_o_gemm(const f16* __restrict__ A, const f16* __restrict__ Bt,
                                                const float* __restrict__ bias,
                                                float* __restrict__ out) {
    __shared__ f16 As[128 * 40];
    __shared__ f16 Bs[128 * 40];
    int m0 = blockIdx.x * 128, n0 = blockIdx.y * 128;
    int t = threadIdx.x, lane = t & 63, w = t >> 6;
    int wr = w >> 1, wc = w & 1;
    f32x4 zero = {0.f, 0.f, 0.f, 0.f};
    f32x4 acc[4][4];
#pragma unroll
    for (int i = 0; i < 4; ++i)
#pragma unroll
        for (int j = 0; j < 4; ++j) acc[i][j] = zero;

    gemm_core(A, Bt, m0, n0, t, lane, wr, wc, As, Bs, acc);

#pragma unroll
    for (int j = 0; j < 4; ++j) {
        int n = n0 + wc * 64 + j * 16 + (lane & 15);
        float bv = bias[n];
#pragma unroll
        for (int i = 0; i < 4; ++i) {
            int m = m0 + wr * 64 + i * 16 + ((lane >> 4) << 2);
#pragma unroll
            for (int r = 0; r < 4; ++r) out[(size_t)(m + r) * 768 + n] = acc[i][j][r] + bv;
        }
    }
}

// ---------------- attention: per (bh, 64-row q-tile); 4 waves x 16 q-rows ----------------
// Pass 1: S = Q*K^T (Q pre-scaled), lsum = rowsum(exp(S)).
// Pass 2: recompute S, P = exp(S)/lsum -> write fp32 attention + stage f16 in LDS -> PV.
__global__ __launch_bounds__(256) void k_attn(const f16* __restrict__ Qh, const f16* __restrict__ Kh,
                                              const f16* __restrict__ Vt, float* __restrict__ attn,
                                              f16* __restrict__ valh) {
    __shared__ f16 smem[64 * 72 * 3];
    f16* Qs = smem;            // reused as Ps (per-wave 16x72 slices) in pass 2
    f16* Ks = smem + 64 * 72;
    f16* Vs = smem + 64 * 72 * 2;
    int qt = blockIdx.x, bh = blockIdx.y;
    int q0 = qt * 64;
    int t = threadIdx.x, lane = t & 63, w = t >> 6;
    const f16* qsrc = Qh + (size_t)bh * 2048 * 64 + (size_t)q0 * 64;
    const f16* ksrc = Kh + (size_t)bh * 2048 * 64;
    const f16* vsrc = Vt + (size_t)bh * 64 * 2048;

    // stage Q tile [64][64] -> Qs (stride 72)
#pragma unroll
    for (int i = 0; i < 2; ++i) {
        int c = t + i * 256;
        int row = c >> 3, cb = (c & 7) * 8;
        *(f16x8*)(Qs + row * 72 + cb) = *(const f16x8*)(qsrc + row * 64 + cb);
    }
    __syncthreads();
    f16x8 aq[2];
#pragma unroll
    for (int f = 0; f < 2; ++f)
        aq[f] = *(const f16x8*)(Qs + (w * 16 + (lane & 15)) * 72 + f * 32 + (lane >> 4) * 8);

    f32x4 zero = {0.f, 0.f, 0.f, 0.f};

    // ---- pass 1: row sums of exp(S) ----
    float lsum[4] = {0.f, 0.f, 0.f, 0.f};
    for (int kt = 0; kt < 32; ++kt) {
#pragma unroll
        for (int i = 0; i < 2; ++i) {
            int c = t + i * 256;
            int row = c >> 3, cb = (c & 7) * 8;
            *(f16x8*)(Ks + row * 72 + cb) =
                *(const f16x8*)(ksrc + (size_t)(kt * 64 + row) * 64 + cb);
        }
        __syncthreads();
#pragma unroll
        for (int s = 0; s < 4; ++s) {
            f16x8 b0 = *(const f16x8*)(Ks + (s * 16 + (lane & 15)) * 72 + (lane >> 4) * 8);
            f16x8 b1 = *(const f16x8*)(Ks + (s * 16 + (lane & 15)) * 72 + 32 + (lane >> 4) * 8);
            f32x4 sacc = MFMA16(aq[0], b0, zero);
            sacc = MFMA16(aq[1], b1, sacc);
#pragma unroll
            for (int r = 0; r < 4; ++r) lsum[r] += __expf(sacc[r]);
        }
        __syncthreads();
    }
#pragma unroll
    for (int r = 0; r < 4; ++r) {
#pragma unroll
        for (int off = 1; off < 16; off <<= 1) lsum[r] += __shfl_xor(lsum[r], off, 64);
    }
    float linv[4];
#pragma unroll
    for (int r = 0; r < 4; ++r) linv[r] = 1.0f / lsum[r];

    // ---- pass 2: P write + PV ----
    f32x4 accv[4];
#pragma unroll
    for (int j = 0; j < 4; ++j) accv[j] = zero;
    f16* Ps = Qs + w * 16 * 72;
    float* attn_base = attn + ((size_t)bh * 2048 + q0 + w * 16) * 2048;

    for (int kt = 0; kt < 32; ++kt) {
#pragma unroll
        for (int i = 0; i < 2; ++i) {
            int c = t + i * 256;
            int row = c >> 3, cb = (c & 7) * 8;
            *(f16x8*)(Ks + row * 72 + cb) =
                *(const f16x8*)(ksrc + (size_t)(kt * 64 + row) * 64 + cb);
            *(f16x8*)(Vs + row * 72 + cb) =
                *(const f16x8*)(vsrc + (size_t)row * 2048 + kt * 64 + cb);
        }
        __syncthreads();
#pragma unroll
        for (int s = 0; s < 4; ++s) {
            f16x8 b0 = *(const f16x8*)(Ks + (s * 16 + (lane & 15)) * 72 + (lane >> 4) * 8);
            f16x8 b1 = *(const f16x8*)(Ks + (s * 16 + (lane & 15)) * 72 + 32 + (lane >> 4) * 8);
            f32x4 sacc = MFMA16(aq[0], b0, zero);
            sacc = MFMA16(aq[1], b1, sacc);
#pragma unroll
            for (int r = 0; r < 4; ++r) {
                float p = __expf(sacc[r]) * linv[r];
                attn_base[(size_t)((lane >> 4) * 4 + r) * 2048 + kt * 64 + s * 16 + (lane & 15)] = p;
                Ps[((lane >> 4) * 4 + r) * 72 + s * 16 + (lane & 15)] = (f16)p;
            }
        }
        // PV: A = P[16q][64k] (Ps), B = V[64k][64d] (Vs is [d][k])
        f16x8 pa[2];
#pragma unroll
        for (int c2 = 0; c2 < 2; ++c2)
            pa[c2] = *(const f16x8*)(Ps + (lane & 15) * 72 + c2 * 32 + (lane >> 4) * 8);
#pragma unroll
        for (int j = 0; j < 4; ++j) {
#pragma unroll
            for (int c2 = 0; c2 < 2; ++c2) {
                f16x8 bv = *(const f16x8*)(Vs + (j * 16 + (lane & 15)) * 72 + c2 * 32 + (lane >> 4) * 8);
                accv[j] = MFMA16(pa[c2], bv, accv[j]);
            }
        }
        __syncthreads();
    }

    // epilogue: values -> valh [b*2048+t][h*64+d] f16
    int b = bh / 12, h = bh - b * 12;
#pragma unroll
    for (int j = 0; j < 4; ++j) {
#pragma unroll
        for (int r = 0; r < 4; ++r) {
            int rowg = b * 2048 + q0 + w * 16 + (lane >> 4) * 4 + r;
            int col = h * 64 + j * 16 + (lane & 15);
            valh[(size_t)rowg * 768 + col] = (f16)accv[j][r];
        }
    }
}

extern "C" void kernel_launch(void* const* d_in, const int* in_sizes, int n_in,
                              void* d_out, int out_size, void* d_ws, size_t ws_size,
                              hipStream_t stream) {
    const float* x = (const float*)d_in[0];
    const float* wqkv = (const float*)d_in[1];
    const float* bqkv = (const float*)d_in[2];
    const float* wo = (const float*)d_in[3];
    const float* bo = (const float*)d_in[4];

    float* out_o = (float*)d_out;                          // [2,2048,768] fp32
    float* out_attn = out_o + (size_t)2 * 2048 * 768;      // [2,12,2048,2048] fp32

    f16* ws = (f16*)d_ws;
    f16* xh = ws;                       // 3,145,728
    f16* wqkv_t = xh + 3145728;         // 1,769,472  [2304][768]
    f16* wo_t = wqkv_t + 1769472;       // 589,824    [768][768]
    f16* Qh = wo_t + 589824;            // [bh][t][64], pre-scaled by 0.125
    f16* Kh = Qh + 3145728;             // [bh][t][64]
    f16* Vt = Kh + 3145728;             // [bh][64][t]  (transposed)
    f16* valh = Vt + 3145728;           // [4096][768]

    k_convert_x<<<3072, 256, 0, stream>>>(x, xh, 786432);
    k_transpose<<<dim3(36, 12), 256, 0, stream>>>(wqkv, wqkv_t, 768, 2304);
    k_transpose<<<dim3(12, 12), 256, 0, stream>>>(wo, wo_t, 768, 768);
    k_qkv_gemm<<<dim3(32, 18), 256, 0, stream>>>(xh, wqkv_t, bqkv, Qh, Kh, Vt);
    k_attn<<<dim3(32, 24), 256, 0, stream>>>(Qh, Kh, Vt, out_attn, valh);
    k_o_gemm<<<dim3(32, 6), 256, 0, stream>>>(valh, wo_t, bo, out_o);
}